// Round 1
// baseline (411.388 us; speedup 1.0000x reference)
//
#include <hip/hip_runtime.h>
#include <math.h>

#define N_NODES 50000
#define N_EDGES 800000
#define N_EVAL  500000

// ---------------- CSR build ----------------

__global__ void k_hist(const int* __restrict__ dst, int* __restrict__ deg) {
    int e = blockIdx.x * 256 + threadIdx.x;
    if (e < N_EDGES) atomicAdd(&deg[dst[e]], 1);
}

// Single-block exclusive scan over N_NODES degrees -> off[], cur[].
// 1024 threads, 4 elems/thread, shuffle wave-scan + LDS cross-wave.
__global__ __launch_bounds__(1024) void k_scan(const int* __restrict__ deg,
                                               int* __restrict__ off,
                                               int* __restrict__ cur) {
    __shared__ int wsum[16];
    __shared__ int carry_s;
    const int tid  = threadIdx.x;
    const int lane = tid & 63;
    const int wid  = tid >> 6;
    if (tid == 0) carry_s = 0;
    __syncthreads();
    for (int base = 0; base < N_NODES; base += 4096) {
        int idx = base + tid * 4;
        int4 v = make_int4(0, 0, 0, 0);
        if (idx + 3 < N_NODES) {
            v = *(const int4*)(deg + idx);
        } else if (idx < N_NODES) {
            v.x = deg[idx];
            if (idx + 1 < N_NODES) v.y = deg[idx + 1];
            if (idx + 2 < N_NODES) v.z = deg[idx + 2];
        }
        int tsum = v.x + v.y + v.z + v.w;
        int s = tsum;
        #pragma unroll
        for (int d = 1; d < 64; d <<= 1) {
            int o = __shfl_up(s, (unsigned)d, 64);
            if (lane >= d) s += o;
        }
        if (lane == 63) wsum[wid] = s;
        __syncthreads();
        if (wid == 0) {
            int ws = (lane < 16) ? wsum[lane] : 0;
            #pragma unroll
            for (int d = 1; d < 16; d <<= 1) {
                int o = __shfl_up(ws, (unsigned)d, 64);
                if (lane >= d) ws += o;
            }
            if (lane < 16) wsum[lane] = ws;
        }
        __syncthreads();
        int waveoff = (wid > 0) ? wsum[wid - 1] : 0;
        int excl = carry_s + waveoff + (s - tsum);
        if (idx < N_NODES) {
            int o0 = excl, o1 = o0 + v.x, o2 = o1 + v.y, o3 = o2 + v.z;
            off[idx] = o0; cur[idx] = o0;
            if (idx + 1 < N_NODES) { off[idx + 1] = o1; cur[idx + 1] = o1; }
            if (idx + 2 < N_NODES) { off[idx + 2] = o2; cur[idx + 2] = o2; }
            if (idx + 3 < N_NODES) { off[idx + 3] = o3; cur[idx + 3] = o3; }
        }
        __syncthreads();
        if (tid == 0) carry_s += wsum[15];
        __syncthreads();
    }
    if (tid == 0) off[N_NODES] = carry_s;
}

__global__ void k_fill(const int* __restrict__ src, const int* __restrict__ dst,
                       int* __restrict__ cur, int* __restrict__ csr) {
    int e = blockIdx.x * 256 + threadIdx.x;
    if (e < N_EDGES) {
        int slot = atomicAdd(&cur[dst[e]], 1);
        csr[slot] = src[e];
    }
}

// ---------------- Aggregation: aggr[v] = sum_{u in csr[off[v]..off[v+1])} x[u] ----
// thread = (node v, float4 chunk c of 24). 24 consecutive lanes cover one row.
__global__ void k_aggr(const float* __restrict__ x, const int* __restrict__ off,
                       const int* __restrict__ csr, float* __restrict__ out) {
    int gt = blockIdx.x * 256 + threadIdx.x;
    if (gt >= N_NODES * 24) return;
    int v = gt / 24;
    int c = gt - v * 24;
    int beg = off[v], end = off[v + 1];
    float4 acc = make_float4(0.f, 0.f, 0.f, 0.f);
    for (int i = beg; i < end; ++i) {
        int u = csr[i];
        float4 t = *(const float4*)(x + (size_t)u * 96 + c * 4);
        acc.x += t.x; acc.y += t.y; acc.z += t.z; acc.w += t.w;
    }
    *(float4*)(out + (size_t)v * 96 + c * 4) = acc;
}

// ---------------- Fused GEMM: out = [RELU](P @ Wl + X @ Wr + b) ----------------
// Block: 256 threads = 32 j-lanes x 8 row-threads; 64 rows x 96 cols per block.
// K = 192 in 6 chunks of 32. LDS: W-chunk 32x96 (12.3 KB) + xT 32x68-padded (8.7 KB).
template <int RELU>
__global__ __launch_bounds__(256) void k_gemm(const float* __restrict__ P,
                                              const float* __restrict__ X,
                                              const float* __restrict__ Wl,
                                              const float* __restrict__ Wr,
                                              const float* __restrict__ bias,
                                              float* __restrict__ out) {
    __shared__ float Ws[32 * 96];
    __shared__ float xT[32 * 68];
    const int tid = threadIdx.x;
    const int j   = tid & 31;
    const int ty  = tid >> 5;         // 0..7, owns rows ty*8 .. ty*8+7
    const int v0  = blockIdx.x * 64;

    float acc[8][3];
    float b0 = bias[j], b1 = bias[j + 32], b2 = bias[j + 64];
    #pragma unroll
    for (int r = 0; r < 8; ++r) { acc[r][0] = b0; acc[r][1] = b1; acc[r][2] = b2; }

    const int sr = tid >> 2;          // staging row 0..63
    const int sc = tid & 3;           // staging col-group 0..3
    int sv = v0 + sr; if (sv >= N_NODES) sv = N_NODES - 1;  // clamp tail (safe: same-block rows)

    for (int kc = 0; kc < 6; ++kc) {
        const float* W = (kc < 3 ? Wl : Wr) + (kc % 3) * (32 * 96);
        const float* M = (kc < 3 ? P : X);
        const int kbase = (kc % 3) * 32;
        __syncthreads();
        // stage W chunk: 3072 contiguous floats, coalesced float4
        #pragma unroll
        for (int i = 0; i < 3; ++i) {
            int f = tid + i * 256;
            *(float4*)(Ws + f * 4) = *(const float4*)(W + f * 4);
        }
        // stage x tile transposed: xT[k][r], row stride 68 (pad: 16B-aligned, <=2-way bank alias)
        {
            const float* rowp = M + (size_t)sv * 96 + kbase;
            float4 a = *(const float4*)(rowp + sc * 4);
            float4 b = *(const float4*)(rowp + sc * 4 + 16);
            int k0 = sc * 4;
            xT[(k0 + 0) * 68 + sr] = a.x;
            xT[(k0 + 1) * 68 + sr] = a.y;
            xT[(k0 + 2) * 68 + sr] = a.z;
            xT[(k0 + 3) * 68 + sr] = a.w;
            xT[(k0 + 16) * 68 + sr] = b.x;
            xT[(k0 + 17) * 68 + sr] = b.y;
            xT[(k0 + 18) * 68 + sr] = b.z;
            xT[(k0 + 19) * 68 + sr] = b.w;
        }
        __syncthreads();
        #pragma unroll 8
        for (int kk = 0; kk < 32; ++kk) {
            float w0 = Ws[kk * 96 + j];
            float w1 = Ws[kk * 96 + j + 32];
            float w2 = Ws[kk * 96 + j + 64];
            float4 xa = *(const float4*)(xT + kk * 68 + ty * 8);
            float4 xb = *(const float4*)(xT + kk * 68 + ty * 8 + 4);
#define ROWFMA(r, xv)                                   \
            acc[r][0] = fmaf(xv, w0, acc[r][0]);        \
            acc[r][1] = fmaf(xv, w1, acc[r][1]);        \
            acc[r][2] = fmaf(xv, w2, acc[r][2]);
            ROWFMA(0, xa.x) ROWFMA(1, xa.y) ROWFMA(2, xa.z) ROWFMA(3, xa.w)
            ROWFMA(4, xb.x) ROWFMA(5, xb.y) ROWFMA(6, xb.z) ROWFMA(7, xb.w)
#undef ROWFMA
        }
    }
    #pragma unroll
    for (int r = 0; r < 8; ++r) {
        int v = v0 + ty * 8 + r;
        if (v < N_NODES) {
            float o0 = acc[r][0], o1 = acc[r][1], o2 = acc[r][2];
            if (RELU) { o0 = fmaxf(o0, 0.f); o1 = fmaxf(o1, 0.f); o2 = fmaxf(o2, 0.f); }
            out[(size_t)v * 96 + j]      = o0;
            out[(size_t)v * 96 + j + 32] = o1;
            out[(size_t)v * 96 + j + 64] = o2;
        }
    }
}

// ---------------- Edge scoring: sigmoid(dot(h[E0], h[E1])) ----------------
// 8 lanes per edge, each lane covers 12 floats (3 x float4), shuffle-reduce.
__global__ void k_score(const float* __restrict__ h, const int* __restrict__ E,
                        float* __restrict__ out) {
    int t = blockIdx.x * 256 + threadIdx.x;
    int e = t >> 3, sub = t & 7;
    if (e >= N_EVAL) return;
    int s = E[e];
    int d = E[N_EVAL + e];
    const float* ps = h + (size_t)s * 96 + sub * 12;
    const float* pd = h + (size_t)d * 96 + sub * 12;
    float dot = 0.f;
    #pragma unroll
    for (int i = 0; i < 3; ++i) {
        float4 a = *(const float4*)(ps + i * 4);
        float4 b = *(const float4*)(pd + i * 4);
        dot += a.x * b.x + a.y * b.y + a.z * b.z + a.w * b.w;
    }
    dot += __shfl_xor(dot, 1, 64);
    dot += __shfl_xor(dot, 2, 64);
    dot += __shfl_xor(dot, 4, 64);
    if (sub == 0) out[e] = 1.f / (1.f + expf(-dot));
}

// ---------------- launch ----------------

extern "C" void kernel_launch(void* const* d_in, const int* in_sizes, int n_in,
                              void* d_out, int out_size, void* d_ws, size_t ws_size,
                              hipStream_t stream) {
    const float* Features = (const float*)d_in[0];
    const int*   A        = (const int*)d_in[1];   // [2, N_EDGES] int32 (JAX canonicalizes int64->int32)
    const int*   E        = (const int*)d_in[2];   // [2, N_EVAL]
    const float* W1l = (const float*)d_in[3];
    const float* W1r = (const float*)d_in[4];
    const float* b1  = (const float*)d_in[5];
    const float* W2l = (const float*)d_in[6];
    const float* W2r = (const float*)d_in[7];
    const float* b2  = (const float*)d_in[8];
    float* out = (float*)d_out;

    char* p = (char*)d_ws;
    auto alloc = [&](size_t bytes) -> char* {
        char* q = p;
        p += (bytes + 255) & ~(size_t)255;
        return q;
    };
    int*   deg  = (int*)alloc((size_t)N_NODES * 4);
    int*   cur  = (int*)alloc((size_t)N_NODES * 4);
    int*   off  = (int*)alloc((size_t)(N_NODES + 1) * 4);
    int*   csr  = (int*)alloc((size_t)N_EDGES * 4);
    float* bufA = (float*)alloc((size_t)N_NODES * 96 * 4);
    float* bufB = (float*)alloc((size_t)N_NODES * 96 * 4);

    const int* Asrc = A;
    const int* Adst = A + N_EDGES;

    hipMemsetAsync(deg, 0, (size_t)N_NODES * 4, stream);
    k_hist<<<(N_EDGES + 255) / 256, 256, 0, stream>>>(Adst, deg);
    k_scan<<<1, 1024, 0, stream>>>(deg, off, cur);
    k_fill<<<(N_EDGES + 255) / 256, 256, 0, stream>>>(Asrc, Adst, cur, csr);

    // Layer 1: aggr -> bufA ; h1 = relu(bufA@W1l + Features@W1r + b1) -> bufB
    k_aggr<<<(N_NODES * 24 + 255) / 256, 256, 0, stream>>>(Features, off, csr, bufA);
    k_gemm<1><<<(N_NODES + 63) / 64, 256, 0, stream>>>(bufA, Features, W1l, W1r, b1, bufB);

    // Layer 2: aggr(h1) -> bufA ; h2 = bufA@W2l + bufB@W2r + b2 -> bufA (in-place safe per-block)
    k_aggr<<<(N_NODES * 24 + 255) / 256, 256, 0, stream>>>(bufB, off, csr, bufA);
    k_gemm<0><<<(N_NODES + 63) / 64, 256, 0, stream>>>(bufA, bufB, W2l, W2r, b2, bufA);

    // Edge scoring
    k_score<<<(N_EVAL * 8 + 255) / 256, 256, 0, stream>>>(bufA, E, out);
}

// Round 2
// 375.863 us; speedup vs baseline: 1.0945x; 1.0945x over previous
//
#include <hip/hip_runtime.h>
#include <math.h>

#define N_NODES 50000
#define N_EDGES 800000
#define N_EVAL  500000
#define SCAN_NB ((N_NODES + 1023) / 1024)   // 49 blocks

__device__ __forceinline__ float4 f4add(float4 a, float4 b) {
    return make_float4(a.x + b.x, a.y + b.y, a.z + b.z, a.w + b.w);
}
__device__ __forceinline__ float4 f4fma(float s, float4 w, float4 a) {
    return make_float4(fmaf(s, w.x, a.x), fmaf(s, w.y, a.y),
                       fmaf(s, w.z, a.z), fmaf(s, w.w, a.w));
}

// ---------------- CSR build ----------------

__global__ __launch_bounds__(256) void k_hist(const int* __restrict__ dst,
                                              int* __restrict__ deg) {
    int e = blockIdx.x * 256 + threadIdx.x;
    if (e < N_EDGES) atomicAdd(&deg[dst[e]], 1);
}

// Hierarchical scan, stage 1: per-block (1024) exclusive scan -> off, block total -> bsum
__global__ __launch_bounds__(1024) void k_scan1(const int* __restrict__ deg,
                                                int* __restrict__ off,
                                                int* __restrict__ bsum) {
    __shared__ int wsum[16];
    const int idx  = blockIdx.x * 1024 + threadIdx.x;
    const int lane = threadIdx.x & 63;
    const int wid  = threadIdx.x >> 6;
    int v = (idx < N_NODES) ? deg[idx] : 0;
    int s = v;
    #pragma unroll
    for (int d = 1; d < 64; d <<= 1) {
        int o = __shfl_up(s, (unsigned)d, 64);
        if (lane >= d) s += o;
    }
    if (lane == 63) wsum[wid] = s;
    __syncthreads();
    if (wid == 0) {
        int ws = (lane < 16) ? wsum[lane] : 0;
        #pragma unroll
        for (int d = 1; d < 16; d <<= 1) {
            int o = __shfl_up(ws, (unsigned)d, 64);
            if (lane >= d) ws += o;
        }
        if (lane < 16) wsum[lane] = ws;
    }
    __syncthreads();
    int incl = (wid ? wsum[wid - 1] : 0) + s;
    if (idx < N_NODES) off[idx] = incl - v;          // exclusive within block
    if (threadIdx.x == 1023) bsum[blockIdx.x] = incl;
}

// stage 2: one wave scans the 49 block sums in place (-> exclusive), writes total
__global__ __launch_bounds__(64) void k_scan2(int* __restrict__ bsum,
                                              int* __restrict__ off) {
    int lane = threadIdx.x;
    int v = (lane < SCAN_NB) ? bsum[lane] : 0;
    int s = v;
    #pragma unroll
    for (int d = 1; d < 64; d <<= 1) {
        int o = __shfl_up(s, (unsigned)d, 64);
        if (lane >= d) s += o;
    }
    if (lane < SCAN_NB) bsum[lane] = s - v;          // exclusive block prefix
    if (lane == 63) off[N_NODES] = s;                // grand total
}

// stage 3: add block prefix, init cur
__global__ __launch_bounds__(1024) void k_scan3(const int* __restrict__ bsum,
                                                int* __restrict__ off,
                                                int* __restrict__ cur) {
    int idx = blockIdx.x * 1024 + threadIdx.x;
    if (idx < N_NODES) {
        int o = off[idx] + bsum[blockIdx.x];
        off[idx] = o;
        cur[idx] = o;
    }
}

__global__ __launch_bounds__(256) void k_fill(const int* __restrict__ src,
                                              const int* __restrict__ dst,
                                              int* __restrict__ cur,
                                              int* __restrict__ csr) {
    int e = blockIdx.x * 256 + threadIdx.x;
    if (e < N_EDGES) {
        int slot = atomicAdd(&cur[dst[e]], 1);
        csr[slot] = src[e];
    }
}

// ---------------- Aggregation: aggr[v] = sum_{u in csr[off[v]..off[v+1])} x[u] ----
// thread = (node v, float4 chunk c of 24); edges unrolled x8 for MLP.
__global__ __launch_bounds__(256) void k_aggr(const float* __restrict__ x,
                                              const int* __restrict__ off,
                                              const int* __restrict__ csr,
                                              float* __restrict__ out) {
    int gt = blockIdx.x * 256 + threadIdx.x;
    if (gt >= N_NODES * 24) return;
    int v = gt / 24;
    int c = gt - v * 24;
    const float* xp = x + c * 4;
    int beg = off[v], end = off[v + 1];
    float4 a0 = make_float4(0.f, 0.f, 0.f, 0.f);
    float4 a1 = make_float4(0.f, 0.f, 0.f, 0.f);
    int i = beg;
    for (; i + 8 <= end; i += 8) {
        int u0 = csr[i + 0], u1 = csr[i + 1], u2 = csr[i + 2], u3 = csr[i + 3];
        int u4 = csr[i + 4], u5 = csr[i + 5], u6 = csr[i + 6], u7 = csr[i + 7];
        float4 t0 = *(const float4*)(xp + (size_t)u0 * 96);
        float4 t1 = *(const float4*)(xp + (size_t)u1 * 96);
        float4 t2 = *(const float4*)(xp + (size_t)u2 * 96);
        float4 t3 = *(const float4*)(xp + (size_t)u3 * 96);
        float4 t4 = *(const float4*)(xp + (size_t)u4 * 96);
        float4 t5 = *(const float4*)(xp + (size_t)u5 * 96);
        float4 t6 = *(const float4*)(xp + (size_t)u6 * 96);
        float4 t7 = *(const float4*)(xp + (size_t)u7 * 96);
        a0 = f4add(a0, f4add(f4add(t0, t2), f4add(t4, t6)));
        a1 = f4add(a1, f4add(f4add(t1, t3), f4add(t5, t7)));
    }
    for (; i < end; ++i) {
        int u = csr[i];
        a0 = f4add(a0, *(const float4*)(xp + (size_t)u * 96));
    }
    *(float4*)(out + (size_t)v * 96 + c * 4) = f4add(a0, a1);
}

// ---------------- Fused GEMM: out = [RELU](P @ Wl + X @ Wr + b) ----------------
// 192 threads: thread = (col-quad q 0..23, row-group rg 0..7 -> rows rg*8..+7).
// Per k-step: 1 b128 W read + 2 b128 x reads = 3 LDS ops / 32 FMAs.
template <int RELU>
__global__ __launch_bounds__(192) void k_gemm(const float* __restrict__ P,
                                              const float* __restrict__ X,
                                              const float* __restrict__ Wl,
                                              const float* __restrict__ Wr,
                                              const float* __restrict__ bias,
                                              float* __restrict__ out) {
    __shared__ float Ws[32 * 96];        // W chunk [32][96]
    __shared__ float xT[32 * 68];        // x tile transposed [k 0..31][row 0..63], pad 68
    const int tid = threadIdx.x;
    const int q   = tid % 24;
    const int rg  = tid / 24;
    const int v0  = blockIdx.x * 64;

    float4 bv = *(const float4*)(bias + q * 4);
    float4 acc[8];
    #pragma unroll
    for (int r = 0; r < 8; ++r) acc[r] = make_float4(0.f, 0.f, 0.f, 0.f);

    for (int kc = 0; kc < 6; ++kc) {
        const float* W = (kc < 3 ? Wl : Wr) + (kc % 3) * (32 * 96);
        const float* M = (kc < 3 ? P : X);
        const int kbase = (kc % 3) * 32;
        __syncthreads();
        // stage W chunk: 3072 floats = 768 float4 / 192 threads = 4 each
        #pragma unroll
        for (int i = 0; i < 4; ++i) {
            int f = tid + i * 192;
            *(float4*)(Ws + f * 4) = *(const float4*)(W + f * 4);
        }
        // stage x tile transposed: 64 rows x 8 float4
        for (int f = tid; f < 512; f += 192) {
            int row = f >> 3, qd = f & 7;
            int sv = v0 + row; if (sv >= N_NODES) sv = N_NODES - 1;   // clamp tail
            float4 t = *(const float4*)(M + (size_t)sv * 96 + kbase + qd * 4);
            int k0 = qd * 4;
            xT[(k0 + 0) * 68 + row] = t.x;
            xT[(k0 + 1) * 68 + row] = t.y;
            xT[(k0 + 2) * 68 + row] = t.z;
            xT[(k0 + 3) * 68 + row] = t.w;
        }
        __syncthreads();
        #pragma unroll 8
        for (int kk = 0; kk < 32; ++kk) {
            float4 w  = *(const float4*)(Ws + kk * 96 + q * 4);
            float4 xa = *(const float4*)(xT + kk * 68 + rg * 8);
            float4 xb = *(const float4*)(xT + kk * 68 + rg * 8 + 4);
            acc[0] = f4fma(xa.x, w, acc[0]);
            acc[1] = f4fma(xa.y, w, acc[1]);
            acc[2] = f4fma(xa.z, w, acc[2]);
            acc[3] = f4fma(xa.w, w, acc[3]);
            acc[4] = f4fma(xb.x, w, acc[4]);
            acc[5] = f4fma(xb.y, w, acc[5]);
            acc[6] = f4fma(xb.z, w, acc[6]);
            acc[7] = f4fma(xb.w, w, acc[7]);
        }
    }
    #pragma unroll
    for (int r = 0; r < 8; ++r) {
        int v = v0 + rg * 8 + r;
        if (v < N_NODES) {
            float4 o = f4add(acc[r], bv);
            if (RELU) {
                o.x = fmaxf(o.x, 0.f); o.y = fmaxf(o.y, 0.f);
                o.z = fmaxf(o.z, 0.f); o.w = fmaxf(o.w, 0.f);
            }
            *(float4*)(out + (size_t)v * 96 + q * 4) = o;
        }
    }
}

// ---------------- Edge scoring: sigmoid(dot(h[E0], h[E1])) ----------------
__global__ __launch_bounds__(256) void k_score(const float* __restrict__ h,
                                               const int* __restrict__ E,
                                               float* __restrict__ out) {
    int t = blockIdx.x * 256 + threadIdx.x;
    int e = t >> 3, sub = t & 7;
    if (e >= N_EVAL) return;
    int s = E[e];
    int d = E[N_EVAL + e];
    const float* ps = h + (size_t)s * 96 + sub * 12;
    const float* pd = h + (size_t)d * 96 + sub * 12;
    float dot = 0.f;
    #pragma unroll
    for (int i = 0; i < 3; ++i) {
        float4 a = *(const float4*)(ps + i * 4);
        float4 b = *(const float4*)(pd + i * 4);
        dot += a.x * b.x + a.y * b.y + a.z * b.z + a.w * b.w;
    }
    dot += __shfl_xor(dot, 1, 64);
    dot += __shfl_xor(dot, 2, 64);
    dot += __shfl_xor(dot, 4, 64);
    if (sub == 0) out[e] = 1.f / (1.f + expf(-dot));
}

// ---------------- launch ----------------

extern "C" void kernel_launch(void* const* d_in, const int* in_sizes, int n_in,
                              void* d_out, int out_size, void* d_ws, size_t ws_size,
                              hipStream_t stream) {
    const float* Features = (const float*)d_in[0];
    const int*   A        = (const int*)d_in[1];   // [2, N_EDGES] int32
    const int*   E        = (const int*)d_in[2];   // [2, N_EVAL]
    const float* W1l = (const float*)d_in[3];
    const float* W1r = (const float*)d_in[4];
    const float* b1  = (const float*)d_in[5];
    const float* W2l = (const float*)d_in[6];
    const float* W2r = (const float*)d_in[7];
    const float* b2  = (const float*)d_in[8];
    float* out = (float*)d_out;

    char* p = (char*)d_ws;
    auto alloc = [&](size_t bytes) -> char* {
        char* q = p;
        p += (bytes + 255) & ~(size_t)255;
        return q;
    };
    int*   deg  = (int*)alloc((size_t)N_NODES * 4);
    int*   cur  = (int*)alloc((size_t)N_NODES * 4);
    int*   off  = (int*)alloc((size_t)(N_NODES + 1) * 4);
    int*   bsum = (int*)alloc((size_t)64 * 4);
    int*   csr  = (int*)alloc((size_t)N_EDGES * 4);
    float* bufA = (float*)alloc((size_t)N_NODES * 96 * 4);
    float* bufB = (float*)alloc((size_t)N_NODES * 96 * 4);

    const int* Asrc = A;
    const int* Adst = A + N_EDGES;

    hipMemsetAsync(deg, 0, (size_t)N_NODES * 4, stream);
    k_hist<<<(N_EDGES + 255) / 256, 256, 0, stream>>>(Adst, deg);
    k_scan1<<<SCAN_NB, 1024, 0, stream>>>(deg, off, bsum);
    k_scan2<<<1, 64, 0, stream>>>(bsum, off);
    k_scan3<<<SCAN_NB, 1024, 0, stream>>>(bsum, off, cur);
    k_fill<<<(N_EDGES + 255) / 256, 256, 0, stream>>>(Asrc, Adst, cur, csr);

    // Layer 1: aggr -> bufA ; h1 = relu(bufA@W1l + Features@W1r + b1) -> bufB
    k_aggr<<<(N_NODES * 24 + 255) / 256, 256, 0, stream>>>(Features, off, csr, bufA);
    k_gemm<1><<<(N_NODES + 63) / 64, 192, 0, stream>>>(bufA, Features, W1l, W1r, b1, bufB);

    // Layer 2: aggr(h1) -> bufA ; h2 = bufA@W2l + bufB@W2r + b2 -> bufA
    k_aggr<<<(N_NODES * 24 + 255) / 256, 256, 0, stream>>>(bufB, off, csr, bufA);
    k_gemm<0><<<(N_NODES + 63) / 64, 192, 0, stream>>>(bufA, bufB, W2l, W2r, b2, bufA);

    // Edge scoring
    k_score<<<(N_EVAL * 8 + 255) / 256, 256, 0, stream>>>(bufA, E, out);
}

// Round 3
// 368.551 us; speedup vs baseline: 1.1162x; 1.0198x over previous
//
#include <hip/hip_runtime.h>
#include <math.h>

#define N_NODES 50000
#define N_EDGES 800000
#define N_EVAL  500000
#define SCAN_NB ((N_NODES + 1023) / 1024)   // 49 blocks
#define CSTRIDE 16                          // 1 counter per 64B line (anti false-sharing)

__device__ __forceinline__ float4 f4add(float4 a, float4 b) {
    return make_float4(a.x + b.x, a.y + b.y, a.z + b.z, a.w + b.w);
}
__device__ __forceinline__ float4 f4fma(float s, float4 w, float4 a) {
    return make_float4(fmaf(s, w.x, a.x), fmaf(s, w.y, a.y),
                       fmaf(s, w.z, a.z), fmaf(s, w.w, a.w));
}

// ---------------- CSR build ----------------

// Single atomic pass: per-edge rank within its dst + degree histogram (strided counters).
__global__ __launch_bounds__(256) void k_rank(const int* __restrict__ dst,
                                              int* __restrict__ degS,
                                              int* __restrict__ rank) {
    int e = blockIdx.x * 256 + threadIdx.x;
    if (e < N_EDGES) {
        int d = dst[e];
        rank[e] = atomicAdd(&degS[(size_t)d * CSTRIDE], 1);
    }
}

// Hierarchical scan, stage 1: per-block (1024) exclusive scan -> off, block total -> bsum
__global__ __launch_bounds__(1024) void k_scan1(const int* __restrict__ degS,
                                                int* __restrict__ off,
                                                int* __restrict__ bsum) {
    __shared__ int wsum[16];
    const int idx  = blockIdx.x * 1024 + threadIdx.x;
    const int lane = threadIdx.x & 63;
    const int wid  = threadIdx.x >> 6;
    int v = (idx < N_NODES) ? degS[(size_t)idx * CSTRIDE] : 0;
    int s = v;
    #pragma unroll
    for (int d = 1; d < 64; d <<= 1) {
        int o = __shfl_up(s, (unsigned)d, 64);
        if (lane >= d) s += o;
    }
    if (lane == 63) wsum[wid] = s;
    __syncthreads();
    if (wid == 0) {
        int ws = (lane < 16) ? wsum[lane] : 0;
        #pragma unroll
        for (int d = 1; d < 16; d <<= 1) {
            int o = __shfl_up(ws, (unsigned)d, 64);
            if (lane >= d) ws += o;
        }
        if (lane < 16) wsum[lane] = ws;
    }
    __syncthreads();
    int incl = (wid ? wsum[wid - 1] : 0) + s;
    if (idx < N_NODES) off[idx] = incl - v;          // exclusive within block
    if (threadIdx.x == 1023) bsum[blockIdx.x] = incl;
}

// stage 2: one wave scans the 49 block sums in place (-> exclusive), writes total
__global__ __launch_bounds__(64) void k_scan2(int* __restrict__ bsum,
                                              int* __restrict__ off) {
    int lane = threadIdx.x;
    int v = (lane < SCAN_NB) ? bsum[lane] : 0;
    int s = v;
    #pragma unroll
    for (int d = 1; d < 64; d <<= 1) {
        int o = __shfl_up(s, (unsigned)d, 64);
        if (lane >= d) s += o;
    }
    if (lane < SCAN_NB) bsum[lane] = s - v;          // exclusive block prefix
    if (lane == 63) off[N_NODES] = s;                // grand total
}

// stage 3: add block prefix
__global__ __launch_bounds__(1024) void k_scan3(const int* __restrict__ bsum,
                                                int* __restrict__ off) {
    int idx = blockIdx.x * 1024 + threadIdx.x;
    if (idx < N_NODES) off[idx] += bsum[blockIdx.x];
}

// Atomic-free scatter: slot fully determined by off + rank.
__global__ __launch_bounds__(256) void k_fill(const int* __restrict__ src,
                                              const int* __restrict__ dst,
                                              const int* __restrict__ rank,
                                              const int* __restrict__ off,
                                              int* __restrict__ csr) {
    int e = blockIdx.x * 256 + threadIdx.x;
    if (e < N_EDGES) {
        csr[off[dst[e]] + rank[e]] = src[e];
    }
}

// ---------------- Aggregation: aggr[v] = sum_{u in csr[off[v]..off[v+1])} x[u] ----
// thread = (node v, float4 chunk c of 24); edges unrolled x8 for MLP.
__global__ __launch_bounds__(256) void k_aggr(const float* __restrict__ x,
                                              const int* __restrict__ off,
                                              const int* __restrict__ csr,
                                              float* __restrict__ out) {
    int gt = blockIdx.x * 256 + threadIdx.x;
    if (gt >= N_NODES * 24) return;
    int v = gt / 24;
    int c = gt - v * 24;
    const float* xp = x + c * 4;
    int beg = off[v], end = off[v + 1];
    float4 a0 = make_float4(0.f, 0.f, 0.f, 0.f);
    float4 a1 = make_float4(0.f, 0.f, 0.f, 0.f);
    int i = beg;
    for (; i + 8 <= end; i += 8) {
        int u0 = csr[i + 0], u1 = csr[i + 1], u2 = csr[i + 2], u3 = csr[i + 3];
        int u4 = csr[i + 4], u5 = csr[i + 5], u6 = csr[i + 6], u7 = csr[i + 7];
        float4 t0 = *(const float4*)(xp + (size_t)u0 * 96);
        float4 t1 = *(const float4*)(xp + (size_t)u1 * 96);
        float4 t2 = *(const float4*)(xp + (size_t)u2 * 96);
        float4 t3 = *(const float4*)(xp + (size_t)u3 * 96);
        float4 t4 = *(const float4*)(xp + (size_t)u4 * 96);
        float4 t5 = *(const float4*)(xp + (size_t)u5 * 96);
        float4 t6 = *(const float4*)(xp + (size_t)u6 * 96);
        float4 t7 = *(const float4*)(xp + (size_t)u7 * 96);
        a0 = f4add(a0, f4add(f4add(t0, t2), f4add(t4, t6)));
        a1 = f4add(a1, f4add(f4add(t1, t3), f4add(t5, t7)));
    }
    for (; i < end; ++i) {
        int u = csr[i];
        a0 = f4add(a0, *(const float4*)(xp + (size_t)u * 96));
    }
    *(float4*)(out + (size_t)v * 96 + c * 4) = f4add(a0, a1);
}

// ---------------- Fused GEMM: out = [RELU](P @ Wl + X @ Wr + b) ----------------
// 192 threads: thread = (col-quad q 0..23, row-group rg 0..7 -> rows rg*8..+7).
// Software-pipelined staging: next chunk's global loads issued before compute.
template <int RELU>
__global__ __launch_bounds__(192) void k_gemm(const float* __restrict__ P,
                                              const float* __restrict__ X,
                                              const float* __restrict__ Wl,
                                              const float* __restrict__ Wr,
                                              const float* __restrict__ bias,
                                              float* __restrict__ out) {
    __shared__ float Ws[32 * 96];        // W chunk [32][96]
    __shared__ float xT[32 * 68];        // x tile transposed [k][row 0..63], pad 68
    const int tid = threadIdx.x;
    const int q   = tid % 24;
    const int rg  = tid / 24;
    const int v0  = blockIdx.x * 64;

    float4 bv = *(const float4*)(bias + q * 4);
    float4 acc[8];
    #pragma unroll
    for (int r = 0; r < 8; ++r) acc[r] = make_float4(0.f, 0.f, 0.f, 0.f);

    // staging coords for x tile: up to 3 pieces per thread (512 float4 / 192 threads)
    float4 wreg[4];
    float4 xreg[3];

    auto load_chunk = [&](int kc) {
        const float* W = (kc < 3 ? Wl : Wr) + (kc % 3) * (32 * 96);
        const float* M = (kc < 3 ? P : X);
        const int kbase = (kc % 3) * 32;
        #pragma unroll
        for (int i = 0; i < 4; ++i)
            wreg[i] = *(const float4*)(W + (tid + i * 192) * 4);
        int n = 0;
        for (int f = tid; f < 512; f += 192) {
            int row = f >> 3, qd = f & 7;
            int sv = v0 + row; if (sv >= N_NODES) sv = N_NODES - 1;
            xreg[n++] = *(const float4*)(M + (size_t)sv * 96 + kbase + qd * 4);
        }
    };
    auto store_chunk = [&]() {
        #pragma unroll
        for (int i = 0; i < 4; ++i)
            *(float4*)(Ws + (tid + i * 192) * 4) = wreg[i];
        int n = 0;
        for (int f = tid; f < 512; f += 192) {
            int row = f >> 3, qd = f & 7;
            float4 t = xreg[n++];
            int k0 = qd * 4;
            xT[(k0 + 0) * 68 + row] = t.x;
            xT[(k0 + 1) * 68 + row] = t.y;
            xT[(k0 + 2) * 68 + row] = t.z;
            xT[(k0 + 3) * 68 + row] = t.w;
        }
    };

    load_chunk(0);
    for (int kc = 0; kc < 6; ++kc) {
        __syncthreads();                 // previous compute done -> safe to overwrite LDS
        store_chunk();
        if (kc < 5) load_chunk(kc + 1);  // issue next global loads early (latency overlap)
        __syncthreads();
        #pragma unroll 8
        for (int kk = 0; kk < 32; ++kk) {
            float4 w  = *(const float4*)(Ws + kk * 96 + q * 4);
            float4 xa = *(const float4*)(xT + kk * 68 + rg * 8);
            float4 xb = *(const float4*)(xT + kk * 68 + rg * 8 + 4);
            acc[0] = f4fma(xa.x, w, acc[0]);
            acc[1] = f4fma(xa.y, w, acc[1]);
            acc[2] = f4fma(xa.z, w, acc[2]);
            acc[3] = f4fma(xa.w, w, acc[3]);
            acc[4] = f4fma(xb.x, w, acc[4]);
            acc[5] = f4fma(xb.y, w, acc[5]);
            acc[6] = f4fma(xb.z, w, acc[6]);
            acc[7] = f4fma(xb.w, w, acc[7]);
        }
    }
    #pragma unroll
    for (int r = 0; r < 8; ++r) {
        int v = v0 + rg * 8 + r;
        if (v < N_NODES) {
            float4 o = f4add(acc[r], bv);
            if (RELU) {
                o.x = fmaxf(o.x, 0.f); o.y = fmaxf(o.y, 0.f);
                o.z = fmaxf(o.z, 0.f); o.w = fmaxf(o.w, 0.f);
            }
            *(float4*)(out + (size_t)v * 96 + q * 4) = o;
        }
    }
}

// ---------------- Edge scoring: sigmoid(dot(h[E0], h[E1])) ----------------
__global__ __launch_bounds__(256) void k_score(const float* __restrict__ h,
                                               const int* __restrict__ E,
                                               float* __restrict__ out) {
    int t = blockIdx.x * 256 + threadIdx.x;
    int e = t >> 3, sub = t & 7;
    if (e >= N_EVAL) return;
    int s = E[e];
    int d = E[N_EVAL + e];
    const float* ps = h + (size_t)s * 96 + sub * 12;
    const float* pd = h + (size_t)d * 96 + sub * 12;
    float dot = 0.f;
    #pragma unroll
    for (int i = 0; i < 3; ++i) {
        float4 a = *(const float4*)(ps + i * 4);
        float4 b = *(const float4*)(pd + i * 4);
        dot += a.x * b.x + a.y * b.y + a.z * b.z + a.w * b.w;
    }
    dot += __shfl_xor(dot, 1, 64);
    dot += __shfl_xor(dot, 2, 64);
    dot += __shfl_xor(dot, 4, 64);
    if (sub == 0) out[e] = 1.f / (1.f + expf(-dot));
}

// ---------------- launch ----------------

extern "C" void kernel_launch(void* const* d_in, const int* in_sizes, int n_in,
                              void* d_out, int out_size, void* d_ws, size_t ws_size,
                              hipStream_t stream) {
    const float* Features = (const float*)d_in[0];
    const int*   A        = (const int*)d_in[1];   // [2, N_EDGES] int32
    const int*   E        = (const int*)d_in[2];   // [2, N_EVAL]
    const float* W1l = (const float*)d_in[3];
    const float* W1r = (const float*)d_in[4];
    const float* b1  = (const float*)d_in[5];
    const float* W2l = (const float*)d_in[6];
    const float* W2r = (const float*)d_in[7];
    const float* b2  = (const float*)d_in[8];
    float* out = (float*)d_out;

    char* p = (char*)d_ws;
    auto alloc = [&](size_t bytes) -> char* {
        char* q = p;
        p += (bytes + 255) & ~(size_t)255;
        return q;
    };
    int*   degS = (int*)alloc((size_t)N_NODES * CSTRIDE * 4);   // 3.2 MB, 1/line
    int*   rank = (int*)alloc((size_t)N_EDGES * 4);
    int*   off  = (int*)alloc((size_t)(N_NODES + 1) * 4);
    int*   bsum = (int*)alloc((size_t)64 * 4);
    int*   csr  = (int*)alloc((size_t)N_EDGES * 4);
    float* bufA = (float*)alloc((size_t)N_NODES * 96 * 4);
    float* bufB = (float*)alloc((size_t)N_NODES * 96 * 4);

    const int* Asrc = A;
    const int* Adst = A + N_EDGES;

    hipMemsetAsync(degS, 0, (size_t)N_NODES * CSTRIDE * 4, stream);
    k_rank<<<(N_EDGES + 255) / 256, 256, 0, stream>>>(Adst, degS, rank);
    k_scan1<<<SCAN_NB, 1024, 0, stream>>>(degS, off, bsum);
    k_scan2<<<1, 64, 0, stream>>>(bsum, off);
    k_scan3<<<SCAN_NB, 1024, 0, stream>>>(bsum, off);
    k_fill<<<(N_EDGES + 255) / 256, 256, 0, stream>>>(Asrc, Adst, rank, off, csr);

    // Layer 1: aggr -> bufA ; h1 = relu(bufA@W1l + Features@W1r + b1) -> bufB
    k_aggr<<<(N_NODES * 24 + 255) / 256, 256, 0, stream>>>(Features, off, csr, bufA);
    k_gemm<1><<<(N_NODES + 63) / 64, 192, 0, stream>>>(bufA, Features, W1l, W1r, b1, bufB);

    // Layer 2: aggr(h1) -> bufA ; h2 = bufA@W2l + bufB@W2r + b2 -> bufA
    k_aggr<<<(N_NODES * 24 + 255) / 256, 256, 0, stream>>>(bufB, off, csr, bufA);
    k_gemm<0><<<(N_NODES + 63) / 64, 192, 0, stream>>>(bufA, bufB, W2l, W2r, b2, bufA);

    // Edge scoring
    k_score<<<(N_EVAL * 8 + 255) / 256, 256, 0, stream>>>(bufA, E, out);
}

// Round 4
// 334.859 us; speedup vs baseline: 1.2285x; 1.1006x over previous
//
#include <hip/hip_runtime.h>
#include <math.h>

#define N_NODES 50000
#define N_EDGES 800000
#define N_EVAL  500000
#define SCAN_NB ((N_NODES + 1023) / 1024)   // 49 blocks
#define CSTRIDE 16                          // 1 counter per 64B line (anti false-sharing)

__device__ __forceinline__ float4 f4add(float4 a, float4 b) {
    return make_float4(a.x + b.x, a.y + b.y, a.z + b.z, a.w + b.w);
}
__device__ __forceinline__ float4 f4fma(float s, float4 w, float4 a) {
    return make_float4(fmaf(s, w.x, a.x), fmaf(s, w.y, a.y),
                       fmaf(s, w.z, a.z), fmaf(s, w.w, a.w));
}

// ---------------- CSR build ----------------

// Single atomic pass: per-edge rank within its dst + degree histogram (strided counters).
__global__ __launch_bounds__(256) void k_rank(const int* __restrict__ dst,
                                              int* __restrict__ degS,
                                              int* __restrict__ rank) {
    int e = blockIdx.x * 256 + threadIdx.x;
    if (e < N_EDGES) {
        int d = dst[e];
        rank[e] = atomicAdd(&degS[(size_t)d * CSTRIDE], 1);
    }
}

// Hierarchical scan, stage 1: per-block (1024) exclusive scan -> off, block total -> bsum
__global__ __launch_bounds__(1024) void k_scan1(const int* __restrict__ degS,
                                                int* __restrict__ off,
                                                int* __restrict__ bsum) {
    __shared__ int wsum[16];
    const int idx  = blockIdx.x * 1024 + threadIdx.x;
    const int lane = threadIdx.x & 63;
    const int wid  = threadIdx.x >> 6;
    int v = (idx < N_NODES) ? degS[(size_t)idx * CSTRIDE] : 0;
    int s = v;
    #pragma unroll
    for (int d = 1; d < 64; d <<= 1) {
        int o = __shfl_up(s, (unsigned)d, 64);
        if (lane >= d) s += o;
    }
    if (lane == 63) wsum[wid] = s;
    __syncthreads();
    if (wid == 0) {
        int ws = (lane < 16) ? wsum[lane] : 0;
        #pragma unroll
        for (int d = 1; d < 16; d <<= 1) {
            int o = __shfl_up(ws, (unsigned)d, 64);
            if (lane >= d) ws += o;
        }
        if (lane < 16) wsum[lane] = ws;
    }
    __syncthreads();
    int incl = (wid ? wsum[wid - 1] : 0) + s;
    if (idx < N_NODES) off[idx] = incl - v;          // exclusive within block
    if (threadIdx.x == 1023) bsum[blockIdx.x] = incl;
}

// stage 2: one wave scans the 49 block sums in place (-> exclusive), writes total
__global__ __launch_bounds__(64) void k_scan2(int* __restrict__ bsum,
                                              int* __restrict__ off) {
    int lane = threadIdx.x;
    int v = (lane < SCAN_NB) ? bsum[lane] : 0;
    int s = v;
    #pragma unroll
    for (int d = 1; d < 64; d <<= 1) {
        int o = __shfl_up(s, (unsigned)d, 64);
        if (lane >= d) s += o;
    }
    if (lane < SCAN_NB) bsum[lane] = s - v;          // exclusive block prefix
    if (lane == 63) off[N_NODES] = s;                // grand total
}

// stage 3: add block prefix
__global__ __launch_bounds__(1024) void k_scan3(const int* __restrict__ bsum,
                                                int* __restrict__ off) {
    int idx = blockIdx.x * 1024 + threadIdx.x;
    if (idx < N_NODES) off[idx] += bsum[blockIdx.x];
}

// Atomic-free scatter: slot fully determined by off + rank.
__global__ __launch_bounds__(256) void k_fill(const int* __restrict__ src,
                                              const int* __restrict__ dst,
                                              const int* __restrict__ rank,
                                              const int* __restrict__ off,
                                              int* __restrict__ csr) {
    int e = blockIdx.x * 256 + threadIdx.x;
    if (e < N_EDGES) {
        csr[off[dst[e]] + rank[e]] = src[e];
    }
}

// ---------------- Aggregation: aggr[v] = sum_{u in csr[off[v]..off[v+1])} x[u] ----
// thread = (node v, float4 chunk c of 24); edges unrolled x8 for MLP.
__global__ __launch_bounds__(256) void k_aggr(const float* __restrict__ x,
                                              const int* __restrict__ off,
                                              const int* __restrict__ csr,
                                              float* __restrict__ out) {
    int gt = blockIdx.x * 256 + threadIdx.x;
    if (gt >= N_NODES * 24) return;
    int v = gt / 24;
    int c = gt - v * 24;
    const float* xp = x + c * 4;
    int beg = off[v], end = off[v + 1];
    float4 a0 = make_float4(0.f, 0.f, 0.f, 0.f);
    float4 a1 = make_float4(0.f, 0.f, 0.f, 0.f);
    int i = beg;
    for (; i + 8 <= end; i += 8) {
        int u0 = csr[i + 0], u1 = csr[i + 1], u2 = csr[i + 2], u3 = csr[i + 3];
        int u4 = csr[i + 4], u5 = csr[i + 5], u6 = csr[i + 6], u7 = csr[i + 7];
        float4 t0 = *(const float4*)(xp + (size_t)u0 * 96);
        float4 t1 = *(const float4*)(xp + (size_t)u1 * 96);
        float4 t2 = *(const float4*)(xp + (size_t)u2 * 96);
        float4 t3 = *(const float4*)(xp + (size_t)u3 * 96);
        float4 t4 = *(const float4*)(xp + (size_t)u4 * 96);
        float4 t5 = *(const float4*)(xp + (size_t)u5 * 96);
        float4 t6 = *(const float4*)(xp + (size_t)u6 * 96);
        float4 t7 = *(const float4*)(xp + (size_t)u7 * 96);
        a0 = f4add(a0, f4add(f4add(t0, t2), f4add(t4, t6)));
        a1 = f4add(a1, f4add(f4add(t1, t3), f4add(t5, t7)));
    }
    for (; i < end; ++i) {
        int u = csr[i];
        a0 = f4add(a0, *(const float4*)(xp + (size_t)u * 96));
    }
    *(float4*)(out + (size_t)v * 96 + c * 4) = f4add(a0, a1);
}

// ---------------- Fused GEMM: out = [RELU](P @ Wl + X @ Wr + b) ----------------
// 192 threads: thread = (col-quad q 0..23, row-group rg 0..7 -> rows rg*8..+7).
// Register-pipelined staging with FULLY STATIC register usage (no dynamic
// array indexing -> no scratch spill; R3's 91MB WRITE_SIZE was xreg[] spilling).
template <int RELU>
__global__ __launch_bounds__(192) void k_gemm(const float* __restrict__ P,
                                              const float* __restrict__ X,
                                              const float* __restrict__ Wl,
                                              const float* __restrict__ Wr,
                                              const float* __restrict__ bias,
                                              float* __restrict__ out) {
    __shared__ float Ws[32 * 96];        // W chunk [32][96]
    __shared__ float xT[32 * 68];        // x tile transposed [k][row 0..63], pad 68
    const int tid = threadIdx.x;
    const int q   = tid % 24;
    const int rg  = tid / 24;
    const int v0  = blockIdx.x * 64;

    // x-staging geometry (static): piece i covers float4 index f = tid + i*192
    const int  row0 = tid >> 3,         qd0 = tid & 7;
    const int  row1 = (tid + 192) >> 3, qd1 = (tid + 192) & 7;
    const int  row2 = (tid + 384) >> 3, qd2 = (tid + 384) & 7;
    const bool has2 = (tid < 128);      // 512 float4 over 192 threads
    int sv0 = v0 + row0; if (sv0 >= N_NODES) sv0 = N_NODES - 1;
    int sv1 = v0 + row1; if (sv1 >= N_NODES) sv1 = N_NODES - 1;
    int sv2 = v0 + row2; if (sv2 >= N_NODES) sv2 = N_NODES - 1;

    float4 bv = *(const float4*)(bias + q * 4);
    float4 acc[8];
    #pragma unroll
    for (int r = 0; r < 8; ++r) acc[r] = make_float4(0.f, 0.f, 0.f, 0.f);

    float4 wreg0, wreg1, wreg2, wreg3;
    float4 xreg0, xreg1, xreg2;

    auto load_chunk = [&](int kc) {
        const float* W = (kc < 3 ? Wl : Wr) + (kc % 3) * (32 * 96);
        const float* M = (kc < 3 ? P : X);
        const int kbase = (kc % 3) * 32;
        wreg0 = *(const float4*)(W + (tid + 0 * 192) * 4);
        wreg1 = *(const float4*)(W + (tid + 1 * 192) * 4);
        wreg2 = *(const float4*)(W + (tid + 2 * 192) * 4);
        wreg3 = *(const float4*)(W + (tid + 3 * 192) * 4);
        xreg0 = *(const float4*)(M + (size_t)sv0 * 96 + kbase + qd0 * 4);
        xreg1 = *(const float4*)(M + (size_t)sv1 * 96 + kbase + qd1 * 4);
        if (has2) xreg2 = *(const float4*)(M + (size_t)sv2 * 96 + kbase + qd2 * 4);
    };
    auto store_chunk = [&]() {
        *(float4*)(Ws + (tid + 0 * 192) * 4) = wreg0;
        *(float4*)(Ws + (tid + 1 * 192) * 4) = wreg1;
        *(float4*)(Ws + (tid + 2 * 192) * 4) = wreg2;
        *(float4*)(Ws + (tid + 3 * 192) * 4) = wreg3;
        int k0 = qd0 * 4;
        xT[(k0 + 0) * 68 + row0] = xreg0.x;
        xT[(k0 + 1) * 68 + row0] = xreg0.y;
        xT[(k0 + 2) * 68 + row0] = xreg0.z;
        xT[(k0 + 3) * 68 + row0] = xreg0.w;
        int k1 = qd1 * 4;
        xT[(k1 + 0) * 68 + row1] = xreg1.x;
        xT[(k1 + 1) * 68 + row1] = xreg1.y;
        xT[(k1 + 2) * 68 + row1] = xreg1.z;
        xT[(k1 + 3) * 68 + row1] = xreg1.w;
        if (has2) {
            int k2 = qd2 * 4;
            xT[(k2 + 0) * 68 + row2] = xreg2.x;
            xT[(k2 + 1) * 68 + row2] = xreg2.y;
            xT[(k2 + 2) * 68 + row2] = xreg2.z;
            xT[(k2 + 3) * 68 + row2] = xreg2.w;
        }
    };

    load_chunk(0);
    for (int kc = 0; kc < 6; ++kc) {
        __syncthreads();                 // previous compute done -> safe to overwrite LDS
        store_chunk();
        if (kc < 5) load_chunk(kc + 1);  // issue next global loads early (latency overlap)
        __syncthreads();
        #pragma unroll 8
        for (int kk = 0; kk < 32; ++kk) {
            float4 w  = *(const float4*)(Ws + kk * 96 + q * 4);
            float4 xa = *(const float4*)(xT + kk * 68 + rg * 8);
            float4 xb = *(const float4*)(xT + kk * 68 + rg * 8 + 4);
            acc[0] = f4fma(xa.x, w, acc[0]);
            acc[1] = f4fma(xa.y, w, acc[1]);
            acc[2] = f4fma(xa.z, w, acc[2]);
            acc[3] = f4fma(xa.w, w, acc[3]);
            acc[4] = f4fma(xb.x, w, acc[4]);
            acc[5] = f4fma(xb.y, w, acc[5]);
            acc[6] = f4fma(xb.z, w, acc[6]);
            acc[7] = f4fma(xb.w, w, acc[7]);
        }
    }
    #pragma unroll
    for (int r = 0; r < 8; ++r) {
        int v = v0 + rg * 8 + r;
        if (v < N_NODES) {
            float4 o = f4add(acc[r], bv);
            if (RELU) {
                o.x = fmaxf(o.x, 0.f); o.y = fmaxf(o.y, 0.f);
                o.z = fmaxf(o.z, 0.f); o.w = fmaxf(o.w, 0.f);
            }
            *(float4*)(out + (size_t)v * 96 + q * 4) = o;
        }
    }
}

// ---------------- Edge scoring: sigmoid(dot(h[E0], h[E1])) ----------------
__global__ __launch_bounds__(256) void k_score(const float* __restrict__ h,
                                               const int* __restrict__ E,
                                               float* __restrict__ out) {
    int t = blockIdx.x * 256 + threadIdx.x;
    int e = t >> 3, sub = t & 7;
    if (e >= N_EVAL) return;
    int s = E[e];
    int d = E[N_EVAL + e];
    const float* ps = h + (size_t)s * 96 + sub * 12;
    const float* pd = h + (size_t)d * 96 + sub * 12;
    float dot = 0.f;
    #pragma unroll
    for (int i = 0; i < 3; ++i) {
        float4 a = *(const float4*)(ps + i * 4);
        float4 b = *(const float4*)(pd + i * 4);
        dot += a.x * b.x + a.y * b.y + a.z * b.z + a.w * b.w;
    }
    dot += __shfl_xor(dot, 1, 64);
    dot += __shfl_xor(dot, 2, 64);
    dot += __shfl_xor(dot, 4, 64);
    if (sub == 0) out[e] = 1.f / (1.f + expf(-dot));
}

// ---------------- launch ----------------

extern "C" void kernel_launch(void* const* d_in, const int* in_sizes, int n_in,
                              void* d_out, int out_size, void* d_ws, size_t ws_size,
                              hipStream_t stream) {
    const float* Features = (const float*)d_in[0];
    const int*   A        = (const int*)d_in[1];   // [2, N_EDGES] int32
    const int*   E        = (const int*)d_in[2];   // [2, N_EVAL]
    const float* W1l = (const float*)d_in[3];
    const float* W1r = (const float*)d_in[4];
    const float* b1  = (const float*)d_in[5];
    const float* W2l = (const float*)d_in[6];
    const float* W2r = (const float*)d_in[7];
    const float* b2  = (const float*)d_in[8];
    float* out = (float*)d_out;

    char* p = (char*)d_ws;
    auto alloc = [&](size_t bytes) -> char* {
        char* q = p;
        p += (bytes + 255) & ~(size_t)255;
        return q;
    };
    int*   degS = (int*)alloc((size_t)N_NODES * CSTRIDE * 4);   // 3.2 MB, 1/line
    int*   rank = (int*)alloc((size_t)N_EDGES * 4);
    int*   off  = (int*)alloc((size_t)(N_NODES + 1) * 4);
    int*   bsum = (int*)alloc((size_t)64 * 4);
    int*   csr  = (int*)alloc((size_t)N_EDGES * 4);
    float* bufA = (float*)alloc((size_t)N_NODES * 96 * 4);
    float* bufB = (float*)alloc((size_t)N_NODES * 96 * 4);

    const int* Asrc = A;
    const int* Adst = A + N_EDGES;

    hipMemsetAsync(degS, 0, (size_t)N_NODES * CSTRIDE * 4, stream);
    k_rank<<<(N_EDGES + 255) / 256, 256, 0, stream>>>(Adst, degS, rank);
    k_scan1<<<SCAN_NB, 1024, 0, stream>>>(degS, off, bsum);
    k_scan2<<<1, 64, 0, stream>>>(bsum, off);
    k_scan3<<<SCAN_NB, 1024, 0, stream>>>(bsum, off);
    k_fill<<<(N_EDGES + 255) / 256, 256, 0, stream>>>(Asrc, Adst, rank, off, csr);

    // Layer 1: aggr -> bufA ; h1 = relu(bufA@W1l + Features@W1r + b1) -> bufB
    k_aggr<<<(N_NODES * 24 + 255) / 256, 256, 0, stream>>>(Features, off, csr, bufA);
    k_gemm<1><<<(N_NODES + 63) / 64, 192, 0, stream>>>(bufA, Features, W1l, W1r, b1, bufB);

    // Layer 2: aggr(h1) -> bufA ; h2 = bufA@W2l + bufB@W2r + b2 -> bufA
    k_aggr<<<(N_NODES * 24 + 255) / 256, 256, 0, stream>>>(bufB, off, csr, bufA);
    k_gemm<0><<<(N_NODES + 63) / 64, 192, 0, stream>>>(bufA, bufB, W2l, W2r, b2, bufA);

    // Edge scoring
    k_score<<<(N_EVAL * 8 + 255) / 256, 256, 0, stream>>>(bufA, E, out);
}